// Round 1
// baseline (1058.578 us; speedup 1.0000x reference)
//
#include <hip/hip_runtime.h>
#include <math.h>

#define NIMG 16
#define FH 1080
#define FW 1920
#define HHh 540
#define HWw 960
#define FHW (FH*FW)        // 2073600
#define TMPW (HHh*FW)      // 1036800
#define HHW (HHh*HWw)      // 518400
#define NG 9801

struct GW { float w[7]; };

__device__ const float FR[36][2] = {
 {0.338f, 10.f}, {0.017204f, 0.806612f}, {0.236f, 1.642f}, {-0.123884f, 0.20293f},
 {0.000155f, 0.712298f}, {0.001122f, 0.470257f}, {0.244f, 1.641f}, {-0.123586f, 0.179083f},
 {0.000152f, 0.710456f}, {0.000975f, 0.470984f}, {0.249f, 1.555f}, {-0.135687f, 0.100858f},
 {0.000174f, 0.684173f}, {0.000913f, 0.534174f}, {0.258f, 1.561f}, {-0.143408f, 0.100486f},
 {0.000179f, 0.685696f}, {0.000888f, 0.536508f}, {0.471f, 3.264f}, {0.012809f, 0.703171f},
 {0.218f, 1.046f}, {-0.094876f, 0.187459f}, {1.5e-05f, 0.442057f}, {0.001272f, 0.40803f},
 {0.222f, 1.042f}, {-0.115772f, 0.162604f}, {1.6e-05f, 0.444362f}, {0.001374f, 0.40243f},
 {0.227f, 0.996f}, {-0.117188f, 0.098323f}, {3e-05f, 0.531903f}, {0.001122f, 0.369589f},
 {0.228f, 0.99f}, {-0.12243f, 0.098658f}, {2.8e-05f, 0.530092f}, {0.001118f, 0.370399f}
};

__global__ void k_zero(float* p, int n){
  int i = blockIdx.x*blockDim.x + threadIdx.x;
  if (i < n) p[i] = 0.f;
}

// ---------------- luma: y = 255*(.299 r + .587 g + .114 b) ----------------
__global__ __launch_bounds__(256) void k_luma(const float* __restrict__ x, float* __restrict__ y, int n0, int nb){
  long long idx = (long long)blockIdx.x*blockDim.x + threadIdx.x;
  long long tot = (long long)nb*(FHW/4);
  if (idx >= tot) return;
  int n = (int)(idx / (FHW/4));
  int p = (int)(idx - (long long)n*(FHW/4));
  const float4* base = (const float4*)(x + (long long)(n0+n)*3*FHW);
  float4 r = base[p];
  float4 g = base[p + FHW/4];
  float4 b = base[p + 2*(FHW/4)];
  float4 o;
  o.x = 255.0f*(0.299f*r.x + 0.587f*g.x + 0.114f*b.x);
  o.y = 255.0f*(0.299f*r.y + 0.587f*g.y + 0.114f*b.y);
  o.z = 255.0f*(0.299f*r.z + 0.587f*g.z + 0.114f*b.z);
  o.w = 255.0f*(0.299f*r.w + 0.587f*g.w + 0.114f*b.w);
  ((float4*)(y + (long long)n*FHW))[p] = o;
}

// ------------- separable 7x7 gaussian normalize: xn = (y-mu)/(sigma+1) -------------
__global__ __launch_bounds__(256) void k_gnorm(const float* __restrict__ src, float* __restrict__ dst,
                                               int Hi, int Wi, GW gw){
  __shared__ float ly[38][40];
  __shared__ float hs[38][33];
  __shared__ float h2[38][33];
  int n = blockIdx.z;
  const float* im = src + (long long)n*Hi*Wi;
  float* om = dst + (long long)n*Hi*Wi;
  int bx = blockIdx.x*32, by = blockIdx.y*32;
  int tid = threadIdx.x;
  for (int t = tid; t < 38*38; t += 256){
    int r = t / 38, c = t - r*38;
    int gi = by + r - 3, gj = bx + c - 3;
    float v = 0.f;
    if (gi >= 0 && gi < Hi && gj >= 0 && gj < Wi) v = im[(long long)gi*Wi + gj];
    ly[r][c] = v;
  }
  __syncthreads();
  for (int t = tid; t < 38*32; t += 256){
    int r = t >> 5, c = t & 31;
    float s = 0.f, s2 = 0.f;
    #pragma unroll
    for (int k = 0; k < 7; k++){ float v = ly[r][c+k]; s += gw.w[k]*v; s2 += gw.w[k]*v*v; }
    hs[r][c] = s; h2[r][c] = s2;
  }
  __syncthreads();
  int c = tid & 31, r0 = tid >> 5;
  for (int r = r0; r < 32; r += 8){
    float mu = 0.f, m2 = 0.f;
    #pragma unroll
    for (int k = 0; k < 7; k++){ mu += gw.w[k]*hs[r+k][c]; m2 += gw.w[k]*h2[r+k][c]; }
    int gi = by + r, gj = bx + c;
    if (gi < Hi && gj < Wi){
      float yv = ly[r+3][c+3];
      float sig = sqrtf(fabsf(m2 - mu*mu) + 1e-8f);
      om[(long long)gi*Wi + gj] = (yv - mu)/(sig + 1.0f);
    }
  }
}

// ------------- NSS reductions: 22 accumulators per image -------------
// layout per image: [0]=sum x^2, [1]=sum |x|, then per shift k in {(0,1),(1,0),(1,1),(-1,1)}:
//   [2+5k]=cl, [3+5k]=cr, [4+5k]=sum (x<0) x^2, [5+5k]=sum (x>0) x^2, [6+5k]=sum |x|
__global__ __launch_bounds__(256) void k_nss(const float* __restrict__ xn, float* __restrict__ acc,
                                             int Hi, int Wi, int accBase){
  int n = blockIdx.y;
  const float* img = xn + (long long)n*Hi*Wi;
  float a[22];
  #pragma unroll
  for (int k = 0; k < 22; k++) a[k] = 0.f;
  for (int i = blockIdx.x; i < Hi; i += gridDim.x){
    const float* rc = img + (long long)i*Wi;
    const float* rm = img + (long long)((i==0)?(Hi-1):(i-1))*Wi;
    const float* rp = img + (long long)((i==Hi-1)?0:(i+1))*Wi;
    for (int j = threadIdx.x; j < Wi; j += 256){
      int jm = (j==0)?(Wi-1):(j-1);
      float xc = rc[j];
      float xl = rc[jm], xu = rm[j], xul = rm[jm], xdl = rp[jm];
      a[0] += xc*xc;
      a[1] += fabsf(xc);
      float pr[4] = {xc*xl, xc*xu, xc*xul, xc*xdl};
      #pragma unroll
      for (int k = 0; k < 4; k++){
        float pp = pr[k];
        float q = pp*pp;
        if (pp < 0.f){ a[2+5*k] += 1.f; a[4+5*k] += q; }
        else if (pp > 0.f){ a[3+5*k] += 1.f; a[5+5*k] += q; }
        a[6+5*k] += fabsf(pp);
      }
    }
  }
  __shared__ float wsum[4][22];
  int lane = threadIdx.x & 63, wv = threadIdx.x >> 6;
  #pragma unroll
  for (int k = 0; k < 22; k++){
    float v = a[k];
    for (int off = 32; off > 0; off >>= 1) v += __shfl_down(v, off, 64);
    if (lane == 0) wsum[wv][k] = v;
  }
  __syncthreads();
  if (threadIdx.x < 22){
    float s = wsum[0][threadIdx.x]+wsum[1][threadIdx.x]+wsum[2][threadIdx.x]+wsum[3][threadIdx.x];
    atomicAdd(&acc[accBase + n*22 + threadIdx.x], s);
  }
}

// ------------- bicubic half-resize weights (MATLAB-style, mirror indexing) -------------
__device__ double d_cubic(double x){
  double ax = fabs(x), ax2 = ax*ax, ax3 = ax2*ax;
  if (ax <= 1.0) return 1.5*ax3 - 2.5*ax2 + 1.0;
  if (ax <= 2.0) return -0.5*ax3 + 2.5*ax2 - 4.0*ax + 2.0;
  return 0.0;
}

__global__ void k_rsetup(float* __restrict__ wH, int* __restrict__ iH,
                         float* __restrict__ wW, int* __restrict__ iW){
  int t = blockIdx.x*blockDim.x + threadIdx.x;
  int inl, o; float* wp; int* ip;
  if (t < HHh){ inl = FH; wp = wH; ip = iH; o = t; }
  else if (t < HHh + HWw){ inl = FW; wp = wW; ip = iW; o = t - HHh; }
  else return;
  double u = 2.0*(o+1) - 0.5;
  double left = floor(u - 4.0);
  double wv[10]; int idx[10]; double s = 0.0;
  for (int p = 0; p < 10; p++){
    double ind = left + p;                 // 1-indexed tap position
    double xv = (u - ind)*0.5;
    double w = 0.5*d_cubic(xv);
    wv[p] = w; s += w;
    long long L2 = 2*(long long)inl;
    long long m = (long long)ind - 1;
    m = ((m % L2) + L2) % L2;
    idx[p] = (m < inl) ? (int)m : (int)(L2 - 1 - m);
  }
  for (int p = 0; p < 10; p++){
    wp[o*10+p] = (float)(wv[p]/s);
    ip[o*10+p] = idx[p];
  }
}

__global__ __launch_bounds__(256) void k_resizeh(const float* __restrict__ y, float* __restrict__ tmp,
                                                 const float* __restrict__ wH, const int* __restrict__ iH, int nb){
  int t = blockIdx.x*blockDim.x + threadIdx.x;
  int tot = nb*HHh*(FW/4);
  if (t >= tot) return;
  int j = t % (FW/4);
  int o = (t / (FW/4)) % HHh;
  int n = t / (HHh*(FW/4));
  const float* yi = y + (long long)n*FHW;
  float4 s = {0.f,0.f,0.f,0.f};
  for (int p = 0; p < 10; p++){
    float w = wH[o*10+p];
    int r = iH[o*10+p];
    float4 v = ((const float4*)(yi + (long long)r*FW))[j];
    s.x += w*v.x; s.y += w*v.y; s.z += w*v.z; s.w += w*v.w;
  }
  ((float4*)(tmp + (long long)n*TMPW))[o*(FW/4)+j] = s;
}

__global__ __launch_bounds__(256) void k_resizew(const float* __restrict__ tmp, float* __restrict__ yh,
                                                 const float* __restrict__ wW, const int* __restrict__ iW, int nb){
  int t = blockIdx.x*blockDim.x + threadIdx.x;
  int tot = nb*HHW;
  if (t >= tot) return;
  int q = t % HWw;
  int o = (t / HWw) % HHh;
  int n = t / HHW;
  const float* row = tmp + (long long)n*TMPW + (long long)o*FW;
  float s = 0.f;
  for (int p = 0; p < 10; p++) s += wW[q*10+p]*row[iW[q*10+p]];
  yh[(long long)n*HHW + (long long)o*HWw + q] = s;
}

// ------------- gamma ratio table -------------
__global__ void k_rtab(float* __restrict__ rt){
  int i = blockIdx.x*blockDim.x + threadIdx.x;
  if (i >= NG) return;
  float g = (float)(0.2 + 0.001*(double)i);
  double gd = (double)g;
  double r = exp(2.0*lgamma(2.0/gd) - lgamma(1.0/gd) - lgamma(3.0/gd));
  rt[i] = (float)r;
}

// ------------- features + argmin + SVR -------------
__global__ __launch_bounds__(256) void k_final(const float* __restrict__ acc, const float* __restrict__ rt,
                                               const float* __restrict__ sv, const float* __restrict__ coef,
                                               float* __restrict__ out){
  int n = blockIdx.x;
  __shared__ float targ[10];
  __shared__ float sfs[36];
  __shared__ int argi[10];
  __shared__ float slv[8], srv[8], feat[36];
  __shared__ float rbv[4]; __shared__ int rbi[4];
  __shared__ float ws2[4];
  int tid = threadIdx.x;
  if (tid == 0){
    for (int s = 0; s < 2; s++){
      const float* A = acc + (s*NIMG + n)*22;
      double HWs = s ? (double)HHW : (double)FHW;
      double s2m = A[0]/HWs;
      double Em  = A[1]/HWs;
      targ[s*5+0] = (float)(s2m/(Em*Em));
      feat[s*18+1] = (float)s2m;
      for (int k = 0; k < 4; k++){
        double cl = A[2+5*k], cr = A[3+5*k], sl2 = A[4+5*k], sr2 = A[5+5*k], sab = A[6+5*k];
        double sl = sqrt(sl2/cl), sr = sqrt(sr2/cr);
        double gh = sl/sr;
        double rhat = (sab/HWs)*(sab/HWs)/((sl2+sr2)/HWs);
        double rhn = rhat*(gh*gh*gh + 1.0)*(gh + 1.0)/((gh*gh + 1.0)*(gh*gh + 1.0));
        targ[s*5+1+k] = (float)rhn;
        slv[s*4+k] = (float)sl; srv[s*4+k] = (float)sr;
        feat[s*18+2+4*k+2] = (float)(sl2/cl);
        feat[s*18+2+4*k+3] = (float)(sr2/cr);
      }
    }
  }
  __syncthreads();
  for (int tix = 0; tix < 10; tix++){
    float tv = targ[tix];
    float bv = 3.4e38f; int bi = 0;
    for (int i = tid; i < NG; i += 256){
      float d = fabsf(tv - rt[i]);
      if (d < bv){ bv = d; bi = i; }
    }
    for (int off = 32; off > 0; off >>= 1){
      float ov = __shfl_down(bv, off, 64);
      int   oi = __shfl_down(bi, off, 64);
      if (ov < bv || (ov == bv && oi < bi)){ bv = ov; bi = oi; }
    }
    int lane = tid & 63, wv = tid >> 6;
    if (lane == 0){ rbv[wv] = bv; rbi[wv] = bi; }
    __syncthreads();
    if (tid == 0){
      for (int w = 1; w < 4; w++)
        if (rbv[w] < bv || (rbv[w] == bv && rbi[w] < bi)){ bv = rbv[w]; bi = rbi[w]; }
      argi[tix] = bi;
    }
    __syncthreads();
  }
  if (tid == 0){
    for (int s = 0; s < 2; s++){
      feat[s*18+0] = (float)(0.2 + 0.001*(double)argi[s*5]);
      for (int k = 0; k < 4; k++){
        double a = 0.2 + 0.001*(double)argi[s*5+1+k];
        double e = exp(lgamma(2.0/a) - 0.5*(lgamma(1.0/a) + lgamma(3.0/a)));
        feat[s*18+2+4*k+0] = (float)a;
        feat[s*18+2+4*k+1] = (float)(((double)srv[s*4+k] - (double)slv[s*4+k])*e);
      }
    }
    for (int i = 0; i < 36; i++){
      float lo = FR[i][0], hi = FR[i][1];
      sfs[i] = -1.0f + 2.0f*(feat[i]-lo)/(hi-lo);
    }
  }
  __syncthreads();
  float local = 0.f;
  for (int v = tid; v < 600; v += 256){
    float d = 0.f;
    #pragma unroll 4
    for (int i = 0; i < 36; i++){ float df = sfs[i] - sv[v*36+i]; d += df*df; }
    local += expf(-0.05f*d)*coef[v];
  }
  for (int off = 32; off > 0; off >>= 1) local += __shfl_down(local, off, 64);
  int lane = tid & 63, wv = tid >> 6;
  if (lane == 0) ws2[wv] = local;
  __syncthreads();
  if (tid == 0) out[n] = ws2[0]+ws2[1]+ws2[2]+ws2[3] + 153.591f;
}

extern "C" void kernel_launch(void* const* d_in, const int* in_sizes, int n_in,
                              void* d_out, int out_size, void* d_ws, size_t ws_size,
                              hipStream_t stream){
  const float* x    = (const float*)d_in[0];
  const float* sv   = (const float*)d_in[1];
  const float* coef = (const float*)d_in[2];
  float* out = (float*)d_out;
  char* ws = (char*)d_ws;

  // workspace layout
  float* acc = (float*)(ws + 0);        // 2*16*22 = 704 floats
  float* rt  = (float*)(ws + 4096);     // 9801 floats
  float* wH  = (float*)(ws + 49152);    // 540*10
  int*   iH  = (int*)  (ws + 73728);
  float* wW  = (float*)(ws + 98304);    // 960*10
  int*   iW  = (int*)  (ws + 139264);
  float* Ybuf = (float*)(ws + 262144);

  size_t big = (ws_size > 262144) ? ws_size - 262144 : 0;
  int nbmax = (int)(big / (2ull*FHW*4));
  if (nbmax < 1) nbmax = 1;
  if (nbmax > NIMG) nbmax = NIMG;
  float* Bbuf = Ybuf + (size_t)nbmax*FHW;

  // gaussian weights (host, double precision, normalized separable)
  GW gw;
  {
    double g[7], s = 0.0;
    for (int k = 0; k < 7; k++){ double d = k - 3; g[k] = exp(-d*d/(2.0*(7.0/6.0)*(7.0/6.0))); s += g[k]; }
    for (int k = 0; k < 7; k++) gw.w[k] = (float)(g[k]/s);
  }

  k_zero<<<4, 256, 0, stream>>>(acc, 704);
  k_rtab<<<(NG+255)/256, 256, 0, stream>>>(rt);
  k_rsetup<<<(HHh+HWw+255)/256, 256, 0, stream>>>(wH, iH, wW, iW);

  for (int n0 = 0; n0 < NIMG; n0 += nbmax){
    int nb = (NIMG - n0 < nbmax) ? (NIMG - n0) : nbmax;
    // 1. luma
    {
      long long tot = (long long)nb*(FHW/4);
      k_luma<<<(int)((tot+255)/256), 256, 0, stream>>>(x, Ybuf, n0, nb);
    }
    // 2. normalize full scale -> XN (Bbuf)
    {
      dim3 g2((FW+31)/32, (FH+31)/32, nb);
      k_gnorm<<<g2, 256, 0, stream>>>(Ybuf, Bbuf, FH, FW, gw);
    }
    // 3. NSS reductions full scale
    k_nss<<<dim3(64, nb), 256, 0, stream>>>(Bbuf, acc, FH, FW, (0*NIMG + n0)*22);
    // 4. resize H: Y -> TMP (Bbuf, overwrites XN which is now dead)
    {
      int tot = nb*HHh*(FW/4);
      k_resizeh<<<(tot+255)/256, 256, 0, stream>>>(Ybuf, Bbuf, wH, iH, nb);
    }
    // 5. resize W: TMP -> y_half (Ybuf, y now dead)
    {
      int tot = nb*HHW;
      k_resizew<<<(tot+255)/256, 256, 0, stream>>>(Bbuf, Ybuf, wW, iW, nb);
    }
    // 6. normalize half scale -> XNH (Bbuf beyond TMP region)
    float* XNH = Bbuf + (size_t)nbmax*TMPW;
    {
      dim3 g2((HWw+31)/32, (HHh+31)/32, nb);
      k_gnorm<<<g2, 256, 0, stream>>>(Ybuf, XNH, HHh, HWw, gw);
    }
    // 7. NSS reductions half scale
    k_nss<<<dim3(64, nb), 256, 0, stream>>>(XNH, acc, HHh, HWw, (1*NIMG + n0)*22);
  }

  k_final<<<NIMG, 256, 0, stream>>>(acc, rt, sv, coef, out);
}